// Round 1
// baseline (3616.821 us; speedup 1.0000x reference)
//
#include <hip/hip_runtime.h>
#include <math.h>

static __device__ __forceinline__ float sigf(float x) {
  return 1.0f / (1.0f + __expf(-x));
}
static __device__ __forceinline__ float tanhfast(float x) {
  // tanh(x) = 2*sigmoid(2x) - 1 ; saturates correctly for large |x|
  return 2.0f / (1.0f + __expf(-2.0f * x)) - 1.0f;
}

// m = x @ conv_weight   (x:[N,4], w:[4,4] row-major, m:[N,4])
__global__ void conv_m_kernel(const float* __restrict__ x,
                              const float* __restrict__ w,
                              float* __restrict__ m, int n) {
  int i = blockIdx.x * blockDim.x + threadIdx.x;
  if (i >= n) return;
  float4 xv = reinterpret_cast<const float4*>(x)[i];
  float4 mv;
  mv.x = xv.x * w[0] + xv.y * w[4] + xv.z * w[8]  + xv.w * w[12];
  mv.y = xv.x * w[1] + xv.y * w[5] + xv.z * w[9]  + xv.w * w[13];
  mv.z = xv.x * w[2] + xv.y * w[6] + xv.z * w[10] + xv.w * w[14];
  mv.w = xv.x * w[3] + xv.y * w[7] + xv.z * w[11] + xv.w * w[15];
  reinterpret_cast<float4*>(m)[i] = mv;
}

// scatter: summed[dst] += m[src]*w ; cnt[dst] += 1
__global__ void edge_kernel(const int* __restrict__ ei,
                            const float* __restrict__ ew,
                            const float* __restrict__ m,
                            float* __restrict__ summed,
                            float* __restrict__ cnt, int E) {
  int t = blockIdx.x * blockDim.x + threadIdx.x;
  int e0 = t * 4;
  const float4* m4 = reinterpret_cast<const float4*>(m);
  if (e0 + 3 < E && (E & 3) == 0) {
    int4 s4 = *reinterpret_cast<const int4*>(ei + e0);
    int4 d4 = *reinterpret_cast<const int4*>(ei + E + e0);
    float4 w4 = *reinterpret_cast<const float4*>(ew + e0);
    int ss[4] = {s4.x, s4.y, s4.z, s4.w};
    int dd[4] = {d4.x, d4.y, d4.z, d4.w};
    float ww[4] = {w4.x, w4.y, w4.z, w4.w};
#pragma unroll
    for (int k = 0; k < 4; ++k) {
      float4 mv = m4[ss[k]];
      float* p = summed + 4ll * dd[k];
      unsafeAtomicAdd(p + 0, mv.x * ww[k]);
      unsafeAtomicAdd(p + 1, mv.y * ww[k]);
      unsafeAtomicAdd(p + 2, mv.z * ww[k]);
      unsafeAtomicAdd(p + 3, mv.w * ww[k]);
      unsafeAtomicAdd(cnt + dd[k], 1.0f);
    }
  } else {
    for (int e = e0; e < E && e < e0 + 4; ++e) {
      int s = ei[e], d = ei[E + e];
      float w = ew[e];
      float4 mv = m4[s];
      float* p = summed + 4ll * d;
      unsafeAtomicAdd(p + 0, mv.x * w);
      unsafeAtomicAdd(p + 1, mv.y * w);
      unsafeAtomicAdd(p + 2, mv.z * w);
      unsafeAtomicAdd(p + 3, mv.w * w);
      unsafeAtomicAdd(cnt + d, 1.0f);
    }
  }
}

// fused: agg = summed/max(cnt,1); GRUCell; LSTM step; relu+linear head
__global__ __launch_bounds__(256) void node_kernel(
    const float* __restrict__ x,
    const float* __restrict__ summed,
    const float* __restrict__ cnt,
    const float* __restrict__ h0,
    const float* __restrict__ c0,
    const float* __restrict__ gwi, const float* __restrict__ gwh,
    const float* __restrict__ gbi, const float* __restrict__ gbh,
    const float* __restrict__ lwi, const float* __restrict__ lwh,
    const float* __restrict__ lbi, const float* __restrict__ lbh,
    const float* __restrict__ linw, const float* __restrict__ linb,
    float* __restrict__ out, float* __restrict__ hout, float* __restrict__ cout,
    int n) {
  int i = blockIdx.x * blockDim.x + threadIdx.x;
  if (i >= n) return;

  float4 xv = reinterpret_cast<const float4*>(x)[i];
  float4 sv = reinterpret_cast<const float4*>(summed)[i];
  float inv = 1.0f / fmaxf(cnt[i], 1.0f);
  float agg[4] = {sv.x * inv, sv.y * inv, sv.z * inv, sv.w * inv};
  float xa[4] = {xv.x, xv.y, xv.z, xv.w};

  // ---- GRUCell (gate order r,z,n). gi = agg@Wih^T+bih ; gh = x@Whh^T+bhh
  float hc[4];
#pragma unroll
  for (int c = 0; c < 4; ++c) {
    float gi_r = gbi[c],     gh_r = gbh[c];
    float gi_z = gbi[4 + c], gh_z = gbh[4 + c];
    float gi_n = gbi[8 + c], gh_n = gbh[8 + c];
#pragma unroll
    for (int k = 0; k < 4; ++k) {
      gi_r += agg[k] * gwi[c * 4 + k];       gh_r += xa[k] * gwh[c * 4 + k];
      gi_z += agg[k] * gwi[(4 + c) * 4 + k]; gh_z += xa[k] * gwh[(4 + c) * 4 + k];
      gi_n += agg[k] * gwi[(8 + c) * 4 + k]; gh_n += xa[k] * gwh[(8 + c) * 4 + k];
    }
    float r = sigf(gi_r + gh_r);
    float z = sigf(gi_z + gh_z);
    float nn = tanhfast(gi_n + r * gh_n);
    hc[c] = (1.0f - z) * nn + z * xa[c];
  }

  // ---- LSTM single step (gate order i,f,g,o)
  const float4* h04 = reinterpret_cast<const float4*>(h0) + (size_t)i * 8;
  const float4* c04 = reinterpret_cast<const float4*>(c0) + (size_t)i * 8;
  float hp[32];
#pragma unroll
  for (int q = 0; q < 8; ++q) {
    float4 hv = h04[q];
    hp[q * 4 + 0] = hv.x; hp[q * 4 + 1] = hv.y;
    hp[q * 4 + 2] = hv.z; hp[q * 4 + 3] = hv.w;
  }
  const float4* wih4 = reinterpret_cast<const float4*>(lwi);  // 128 rows x 1 float4
  const float4* whh4 = reinterpret_cast<const float4*>(lwh);  // 128 rows x 8 float4
  float oacc = linb[0];
  float4* hout4 = reinterpret_cast<float4*>(hout) + (size_t)i * 8;
  float4* cout4 = reinterpret_cast<float4*>(cout) + (size_t)i * 8;

#pragma unroll
  for (int jc = 0; jc < 8; ++jc) {
    float4 cpv = c04[jc];
    float cpa[4] = {cpv.x, cpv.y, cpv.z, cpv.w};
    float hn[4], cn[4];
#pragma unroll
    for (int jj = 0; jj < 4; ++jj) {
      int j = jc * 4 + jj;
      float gI = lbi[j]      + lbh[j];
      float gF = lbi[32 + j] + lbh[32 + j];
      float gG = lbi[64 + j] + lbh[64 + j];
      float gO = lbi[96 + j] + lbh[96 + j];
      float4 wi = wih4[j], wf = wih4[32 + j], wg = wih4[64 + j], wo = wih4[96 + j];
      gI += hc[0] * wi.x + hc[1] * wi.y + hc[2] * wi.z + hc[3] * wi.w;
      gF += hc[0] * wf.x + hc[1] * wf.y + hc[2] * wf.z + hc[3] * wf.w;
      gG += hc[0] * wg.x + hc[1] * wg.y + hc[2] * wg.z + hc[3] * wg.w;
      gO += hc[0] * wo.x + hc[1] * wo.y + hc[2] * wo.z + hc[3] * wo.w;
#pragma unroll
      for (int q = 0; q < 8; ++q) {
        float4 a = whh4[j * 8 + q];
        float4 b = whh4[(32 + j) * 8 + q];
        float4 g = whh4[(64 + j) * 8 + q];
        float4 o = whh4[(96 + j) * 8 + q];
        float p0 = hp[q * 4 + 0], p1 = hp[q * 4 + 1];
        float p2 = hp[q * 4 + 2], p3 = hp[q * 4 + 3];
        gI += p0 * a.x + p1 * a.y + p2 * a.z + p3 * a.w;
        gF += p0 * b.x + p1 * b.y + p2 * b.z + p3 * b.w;
        gG += p0 * g.x + p1 * g.y + p2 * g.z + p3 * g.w;
        gO += p0 * o.x + p1 * o.y + p2 * o.z + p3 * o.w;
      }
      float ig = sigf(gI), fg = sigf(gF), og = sigf(gO), gg = tanhfast(gG);
      float cnew = fg * cpa[jj] + ig * gg;
      float hnew = og * tanhfast(cnew);
      cn[jj] = cnew; hn[jj] = hnew;
      oacc += fmaxf(hnew, 0.0f) * linw[j];
    }
    hout4[jc] = make_float4(hn[0], hn[1], hn[2], hn[3]);
    cout4[jc] = make_float4(cn[0], cn[1], cn[2], cn[3]);
  }
  out[i] = oacc;
}

extern "C" void kernel_launch(void* const* d_in, const int* in_sizes, int n_in,
                              void* d_out, int out_size, void* d_ws, size_t ws_size,
                              hipStream_t stream) {
  const float* x     = (const float*)d_in[0];
  const int*   ei    = (const int*)d_in[1];
  const float* ew    = (const float*)d_in[2];
  const float* h0    = (const float*)d_in[3];
  const float* c0    = (const float*)d_in[4];
  const float* convw = (const float*)d_in[5];
  const float* gwi   = (const float*)d_in[6];
  const float* gwh   = (const float*)d_in[7];
  const float* gbi   = (const float*)d_in[8];
  const float* gbh   = (const float*)d_in[9];
  const float* lwi   = (const float*)d_in[10];
  const float* lwh   = (const float*)d_in[11];
  const float* lbi   = (const float*)d_in[12];
  const float* lbh   = (const float*)d_in[13];
  const float* linw  = (const float*)d_in[14];
  const float* linb  = (const float*)d_in[15];

  int n = in_sizes[0] / 4;   // N nodes (x is [N,4])
  int E = in_sizes[1] / 2;   // edge count (edge_index is [2,E])

  float* m      = (float*)d_ws;                 // N*4
  float* summed = m + (size_t)n * 4;            // N*4
  float* cntp   = summed + (size_t)n * 4;       // N

  // zero the atomic accumulators (ws is poisoned before every launch)
  hipMemsetAsync(summed, 0, (size_t)n * 5 * sizeof(float), stream);

  conv_m_kernel<<<(n + 255) / 256, 256, 0, stream>>>(x, convw, m, n);

  int et = (E + 3) / 4;
  edge_kernel<<<(et + 255) / 256, 256, 0, stream>>>(ei, ew, m, summed, cntp, E);

  float* out  = (float*)d_out;
  float* hout = out + n;
  float* cout = hout + (size_t)n * 32;
  node_kernel<<<(n + 255) / 256, 256, 0, stream>>>(
      x, summed, cntp, h0, c0,
      gwi, gwh, gbi, gbh, lwi, lwh, lbi, lbh, linw, linb,
      out, hout, cout, n);
}

// Round 2
// 1173.764 us; speedup vs baseline: 3.0814x; 3.0814x over previous
//
#include <hip/hip_runtime.h>
#include <math.h>

#define B_SHIFT 8          // 256 nodes per bucket
#define BMASK   255
#define CHUNK   16384      // edges per binning block
#define NTHR    256

static __device__ __forceinline__ float sigf(float x) {
  return 1.0f / (1.0f + __expf(-x));
}
static __device__ __forceinline__ float tanhfast(float x) {
  return 2.0f / (1.0f + __expf(-2.0f * x)) - 1.0f;
}

// m = x @ conv_weight   (x:[N,4], w:[4,4] row-major, m:[N,4])
__global__ void conv_m_kernel(const float* __restrict__ x,
                              const float* __restrict__ w,
                              float* __restrict__ m, int n) {
  int i = blockIdx.x * blockDim.x + threadIdx.x;
  if (i >= n) return;
  float4 xv = reinterpret_cast<const float4*>(x)[i];
  float4 mv;
  mv.x = xv.x * w[0] + xv.y * w[4] + xv.z * w[8]  + xv.w * w[12];
  mv.y = xv.x * w[1] + xv.y * w[5] + xv.z * w[9]  + xv.w * w[13];
  mv.z = xv.x * w[2] + xv.y * w[6] + xv.z * w[10] + xv.w * w[14];
  mv.w = xv.x * w[3] + xv.y * w[7] + xv.z * w[11] + xv.w * w[15];
  reinterpret_cast<float4*>(m)[i] = mv;
}

// ---------- fast path: bin by dst bucket, then LDS-accumulate ----------

// per-block histogram of dst>>B_SHIFT -> global bucket counts
__global__ __launch_bounds__(NTHR) void hist_kernel(const int* __restrict__ dst,
                                                    int E, int B,
                                                    int* __restrict__ gCnt) {
  __shared__ int h[1024];
  for (int b = threadIdx.x; b < B; b += NTHR) h[b] = 0;
  __syncthreads();
  const int4* d4 = reinterpret_cast<const int4*>(dst);
  int i4base = (int)(((long long)blockIdx.x * CHUNK) >> 2);
  int lim4 = E >> 2;
#pragma unroll
  for (int j = 0; j < 16; ++j) {
    int i4 = i4base + j * NTHR + threadIdx.x;
    if (i4 < lim4) {
      int4 d = d4[i4];
      atomicAdd(&h[d.x >> B_SHIFT], 1);
      atomicAdd(&h[d.y >> B_SHIFT], 1);
      atomicAdd(&h[d.z >> B_SHIFT], 1);
      atomicAdd(&h[d.w >> B_SHIFT], 1);
    }
  }
  // tail (E not multiple of 4) handled by block 0 thread 0
  if (blockIdx.x == 0 && threadIdx.x == 0) {
    for (int e = E & ~3; e < E; ++e) atomicAdd(&h[dst[e] >> B_SHIFT], 1);
  }
  __syncthreads();
  for (int b = threadIdx.x; b < B; b += NTHR) {
    int c = h[b];
    if (c) atomicAdd(&gCnt[b], c);
  }
}

// exclusive prefix over bucket counts (B <= 1024); also seeds cursors
__global__ void scan_kernel(const int* __restrict__ gCnt, int B,
                            int* __restrict__ start, int* __restrict__ cursor) {
  __shared__ int s[1024];
  int t = threadIdx.x;
  int v = (t < B) ? gCnt[t] : 0;
  s[t] = v;
  __syncthreads();
  for (int off = 1; off < 1024; off <<= 1) {
    int u = (t >= off) ? s[t - off] : 0;
    __syncthreads();
    s[t] += u;
    __syncthreads();
  }
  if (t < B) {
    int excl = (t == 0) ? 0 : s[t - 1];
    start[t] = excl;
    cursor[t] = excl;
  }
  if (t == 0) start[B] = s[1023];
}

// scatter edges into bucket-contiguous regions: rec=(src<<8 | dst&255, w)
__global__ __launch_bounds__(NTHR) void bin_kernel(const int* __restrict__ ei,
                                                   const float* __restrict__ ew,
                                                   int E, int B,
                                                   int* __restrict__ cursor,
                                                   int2* __restrict__ binned) {
  __shared__ int h[1024];
  for (int b = threadIdx.x; b < B; b += NTHR) h[b] = 0;
  __syncthreads();
  const int* dst = ei + E;
  const int4* d4 = reinterpret_cast<const int4*>(dst);
  const int4* s4 = reinterpret_cast<const int4*>(ei);
  const float4* w4 = reinterpret_cast<const float4*>(ew);
  int i4base = (int)(((long long)blockIdx.x * CHUNK) >> 2);
  int lim4 = E >> 2;
#pragma unroll
  for (int j = 0; j < 16; ++j) {
    int i4 = i4base + j * NTHR + threadIdx.x;
    if (i4 < lim4) {
      int4 d = d4[i4];
      atomicAdd(&h[d.x >> B_SHIFT], 1);
      atomicAdd(&h[d.y >> B_SHIFT], 1);
      atomicAdd(&h[d.z >> B_SHIFT], 1);
      atomicAdd(&h[d.w >> B_SHIFT], 1);
    }
  }
  __syncthreads();
  // claim global ranges; h[b] becomes this block's running global cursor
  for (int b = threadIdx.x; b < B; b += NTHR) {
    int c = h[b];
    if (c) h[b] = atomicAdd(&cursor[b], c);
  }
  __syncthreads();
#pragma unroll
  for (int j = 0; j < 16; ++j) {
    int i4 = i4base + j * NTHR + threadIdx.x;
    if (i4 < lim4) {
      int4 d = d4[i4];
      int4 s = s4[i4];
      float4 w = w4[i4];
      int p;
      p = atomicAdd(&h[d.x >> B_SHIFT], 1);
      binned[p] = make_int2((s.x << B_SHIFT) | (d.x & BMASK), __float_as_int(w.x));
      p = atomicAdd(&h[d.y >> B_SHIFT], 1);
      binned[p] = make_int2((s.y << B_SHIFT) | (d.y & BMASK), __float_as_int(w.y));
      p = atomicAdd(&h[d.z >> B_SHIFT], 1);
      binned[p] = make_int2((s.z << B_SHIFT) | (d.z & BMASK), __float_as_int(w.z));
      p = atomicAdd(&h[d.w >> B_SHIFT], 1);
      binned[p] = make_int2((s.w << B_SHIFT) | (d.w & BMASK), __float_as_int(w.w));
    }
  }
  if (blockIdx.x == 0 && threadIdx.x == 0) {
    for (int e = E & ~3; e < E; ++e) {
      int d = dst[e];
      int p = atomicAdd(&cursor[d >> B_SHIFT], 1);
      binned[p] = make_int2((ei[e] << B_SHIFT) | (d & BMASK), __float_as_int(ew[e]));
    }
  }
}

// one block per bucket: LDS-accumulate messages, then fused GRU+LSTM+head
__global__ __launch_bounds__(NTHR) void agg_node_kernel(
    const float* __restrict__ x, const float* __restrict__ m,
    const int2* __restrict__ binned, const int* __restrict__ start,
    const float* __restrict__ h0, const float* __restrict__ c0,
    const float* __restrict__ gwi, const float* __restrict__ gwh,
    const float* __restrict__ gbi, const float* __restrict__ gbh,
    const float* __restrict__ lwi, const float* __restrict__ lwh,
    const float* __restrict__ lbi, const float* __restrict__ lbh,
    const float* __restrict__ linw, const float* __restrict__ linb,
    float* __restrict__ out, float* __restrict__ hout, float* __restrict__ cout,
    int n) {
  __shared__ float acc[NTHR * 5];
  int tid = threadIdx.x;
  for (int idx = tid; idx < NTHR * 5; idx += NTHR) acc[idx] = 0.0f;
  __syncthreads();

  int s = start[blockIdx.x], e = start[blockIdx.x + 1];
  const float4* m4 = reinterpret_cast<const float4*>(m);
  for (int i = s + tid; i < e; i += NTHR) {
    int2 r = binned[i];
    int src = r.x >> B_SHIFT;
    int dl = r.x & BMASK;
    float w = __int_as_float(r.y);
    float4 mv = m4[src];
    atomicAdd(&acc[dl * 5 + 0], mv.x * w);
    atomicAdd(&acc[dl * 5 + 1], mv.y * w);
    atomicAdd(&acc[dl * 5 + 2], mv.z * w);
    atomicAdd(&acc[dl * 5 + 3], mv.w * w);
    atomicAdd(&acc[dl * 5 + 4], 1.0f);
  }
  __syncthreads();

  int i = (blockIdx.x << B_SHIFT) + tid;
  if (i >= n) return;

  float inv = 1.0f / fmaxf(acc[tid * 5 + 4], 1.0f);
  float agg[4] = {acc[tid * 5 + 0] * inv, acc[tid * 5 + 1] * inv,
                  acc[tid * 5 + 2] * inv, acc[tid * 5 + 3] * inv};
  float4 xv = reinterpret_cast<const float4*>(x)[i];
  float xa[4] = {xv.x, xv.y, xv.z, xv.w};

  // ---- GRUCell (gate order r,z,n)
  float hc[4];
#pragma unroll
  for (int c = 0; c < 4; ++c) {
    float gi_r = gbi[c],     gh_r = gbh[c];
    float gi_z = gbi[4 + c], gh_z = gbh[4 + c];
    float gi_n = gbi[8 + c], gh_n = gbh[8 + c];
#pragma unroll
    for (int k = 0; k < 4; ++k) {
      gi_r += agg[k] * gwi[c * 4 + k];       gh_r += xa[k] * gwh[c * 4 + k];
      gi_z += agg[k] * gwi[(4 + c) * 4 + k]; gh_z += xa[k] * gwh[(4 + c) * 4 + k];
      gi_n += agg[k] * gwi[(8 + c) * 4 + k]; gh_n += xa[k] * gwh[(8 + c) * 4 + k];
    }
    float r = sigf(gi_r + gh_r);
    float z = sigf(gi_z + gh_z);
    float nn = tanhfast(gi_n + r * gh_n);
    hc[c] = (1.0f - z) * nn + z * xa[c];
  }

  // ---- LSTM single step (gate order i,f,g,o)
  const float4* h04 = reinterpret_cast<const float4*>(h0) + (size_t)i * 8;
  const float4* c04 = reinterpret_cast<const float4*>(c0) + (size_t)i * 8;
  float hp[32];
#pragma unroll
  for (int q = 0; q < 8; ++q) {
    float4 hv = h04[q];
    hp[q * 4 + 0] = hv.x; hp[q * 4 + 1] = hv.y;
    hp[q * 4 + 2] = hv.z; hp[q * 4 + 3] = hv.w;
  }
  const float4* wih4 = reinterpret_cast<const float4*>(lwi);
  const float4* whh4 = reinterpret_cast<const float4*>(lwh);
  float oacc = linb[0];
  float4* hout4 = reinterpret_cast<float4*>(hout) + (size_t)i * 8;
  float4* cout4 = reinterpret_cast<float4*>(cout) + (size_t)i * 8;

#pragma unroll
  for (int jc = 0; jc < 8; ++jc) {
    float4 cpv = c04[jc];
    float cpa[4] = {cpv.x, cpv.y, cpv.z, cpv.w};
    float hn[4], cn[4];
#pragma unroll
    for (int jj = 0; jj < 4; ++jj) {
      int j = jc * 4 + jj;
      float gI = lbi[j]      + lbh[j];
      float gF = lbi[32 + j] + lbh[32 + j];
      float gG = lbi[64 + j] + lbh[64 + j];
      float gO = lbi[96 + j] + lbh[96 + j];
      float4 wi = wih4[j], wf = wih4[32 + j], wg = wih4[64 + j], wo = wih4[96 + j];
      gI += hc[0] * wi.x + hc[1] * wi.y + hc[2] * wi.z + hc[3] * wi.w;
      gF += hc[0] * wf.x + hc[1] * wf.y + hc[2] * wf.z + hc[3] * wf.w;
      gG += hc[0] * wg.x + hc[1] * wg.y + hc[2] * wg.z + hc[3] * wg.w;
      gO += hc[0] * wo.x + hc[1] * wo.y + hc[2] * wo.z + hc[3] * wo.w;
#pragma unroll
      for (int q = 0; q < 8; ++q) {
        float4 a = whh4[j * 8 + q];
        float4 b = whh4[(32 + j) * 8 + q];
        float4 g = whh4[(64 + j) * 8 + q];
        float4 o = whh4[(96 + j) * 8 + q];
        float p0 = hp[q * 4 + 0], p1 = hp[q * 4 + 1];
        float p2 = hp[q * 4 + 2], p3 = hp[q * 4 + 3];
        gI += p0 * a.x + p1 * a.y + p2 * a.z + p3 * a.w;
        gF += p0 * b.x + p1 * b.y + p2 * b.z + p3 * b.w;
        gG += p0 * g.x + p1 * g.y + p2 * g.z + p3 * g.w;
        gO += p0 * o.x + p1 * o.y + p2 * o.z + p3 * o.w;
      }
      float ig = sigf(gI), fg = sigf(gF), og = sigf(gO), gg = tanhfast(gG);
      float cnew = fg * cpa[jj] + ig * gg;
      float hnew = og * tanhfast(cnew);
      cn[jj] = cnew; hn[jj] = hnew;
      oacc += fmaxf(hnew, 0.0f) * linw[j];
    }
    hout4[jc] = make_float4(hn[0], hn[1], hn[2], hn[3]);
    cout4[jc] = make_float4(cn[0], cn[1], cn[2], cn[3]);
  }
  out[i] = oacc;
}

// ---------- fallback path (round-0, correct but atomic-bound) ----------

__global__ void edge_kernel(const int* __restrict__ ei,
                            const float* __restrict__ ew,
                            const float* __restrict__ m,
                            float* __restrict__ summed,
                            float* __restrict__ cnt, int E) {
  int t = blockIdx.x * blockDim.x + threadIdx.x;
  int e0 = t * 4;
  const float4* m4 = reinterpret_cast<const float4*>(m);
  for (int e = e0; e < E && e < e0 + 4; ++e) {
    int s = ei[e], d = ei[E + e];
    float w = ew[e];
    float4 mv = m4[s];
    float* p = summed + 4ll * d;
    unsafeAtomicAdd(p + 0, mv.x * w);
    unsafeAtomicAdd(p + 1, mv.y * w);
    unsafeAtomicAdd(p + 2, mv.z * w);
    unsafeAtomicAdd(p + 3, mv.w * w);
    unsafeAtomicAdd(cnt + d, 1.0f);
  }
}

__global__ __launch_bounds__(NTHR) void node_kernel(
    const float* __restrict__ x, const float* __restrict__ summed,
    const float* __restrict__ cnt,
    const float* __restrict__ h0, const float* __restrict__ c0,
    const float* __restrict__ gwi, const float* __restrict__ gwh,
    const float* __restrict__ gbi, const float* __restrict__ gbh,
    const float* __restrict__ lwi, const float* __restrict__ lwh,
    const float* __restrict__ lbi, const float* __restrict__ lbh,
    const float* __restrict__ linw, const float* __restrict__ linb,
    float* __restrict__ out, float* __restrict__ hout, float* __restrict__ cout,
    int n) {
  int i = blockIdx.x * blockDim.x + threadIdx.x;
  if (i >= n) return;
  float4 sv = reinterpret_cast<const float4*>(summed)[i];
  float inv = 1.0f / fmaxf(cnt[i], 1.0f);
  float agg[4] = {sv.x * inv, sv.y * inv, sv.z * inv, sv.w * inv};
  float4 xv = reinterpret_cast<const float4*>(x)[i];
  float xa[4] = {xv.x, xv.y, xv.z, xv.w};
  float hc[4];
#pragma unroll
  for (int c = 0; c < 4; ++c) {
    float gi_r = gbi[c],     gh_r = gbh[c];
    float gi_z = gbi[4 + c], gh_z = gbh[4 + c];
    float gi_n = gbi[8 + c], gh_n = gbh[8 + c];
#pragma unroll
    for (int k = 0; k < 4; ++k) {
      gi_r += agg[k] * gwi[c * 4 + k];       gh_r += xa[k] * gwh[c * 4 + k];
      gi_z += agg[k] * gwi[(4 + c) * 4 + k]; gh_z += xa[k] * gwh[(4 + c) * 4 + k];
      gi_n += agg[k] * gwi[(8 + c) * 4 + k]; gh_n += xa[k] * gwh[(8 + c) * 4 + k];
    }
    float r = sigf(gi_r + gh_r);
    float z = sigf(gi_z + gh_z);
    float nn = tanhfast(gi_n + r * gh_n);
    hc[c] = (1.0f - z) * nn + z * xa[c];
  }
  const float4* h04 = reinterpret_cast<const float4*>(h0) + (size_t)i * 8;
  const float4* c04 = reinterpret_cast<const float4*>(c0) + (size_t)i * 8;
  float hp[32];
#pragma unroll
  for (int q = 0; q < 8; ++q) {
    float4 hv = h04[q];
    hp[q * 4 + 0] = hv.x; hp[q * 4 + 1] = hv.y;
    hp[q * 4 + 2] = hv.z; hp[q * 4 + 3] = hv.w;
  }
  const float4* wih4 = reinterpret_cast<const float4*>(lwi);
  const float4* whh4 = reinterpret_cast<const float4*>(lwh);
  float oacc = linb[0];
  float4* hout4 = reinterpret_cast<float4*>(hout) + (size_t)i * 8;
  float4* cout4 = reinterpret_cast<float4*>(cout) + (size_t)i * 8;
#pragma unroll
  for (int jc = 0; jc < 8; ++jc) {
    float4 cpv = c04[jc];
    float cpa[4] = {cpv.x, cpv.y, cpv.z, cpv.w};
    float hn[4], cn[4];
#pragma unroll
    for (int jj = 0; jj < 4; ++jj) {
      int j = jc * 4 + jj;
      float gI = lbi[j]      + lbh[j];
      float gF = lbi[32 + j] + lbh[32 + j];
      float gG = lbi[64 + j] + lbh[64 + j];
      float gO = lbi[96 + j] + lbh[96 + j];
      float4 wi = wih4[j], wf = wih4[32 + j], wg = wih4[64 + j], wo = wih4[96 + j];
      gI += hc[0] * wi.x + hc[1] * wi.y + hc[2] * wi.z + hc[3] * wi.w;
      gF += hc[0] * wf.x + hc[1] * wf.y + hc[2] * wf.z + hc[3] * wf.w;
      gG += hc[0] * wg.x + hc[1] * wg.y + hc[2] * wg.z + hc[3] * wg.w;
      gO += hc[0] * wo.x + hc[1] * wo.y + hc[2] * wo.z + hc[3] * wo.w;
#pragma unroll
      for (int q = 0; q < 8; ++q) {
        float4 a = whh4[j * 8 + q];
        float4 b = whh4[(32 + j) * 8 + q];
        float4 g = whh4[(64 + j) * 8 + q];
        float4 o = whh4[(96 + j) * 8 + q];
        float p0 = hp[q * 4 + 0], p1 = hp[q * 4 + 1];
        float p2 = hp[q * 4 + 2], p3 = hp[q * 4 + 3];
        gI += p0 * a.x + p1 * a.y + p2 * a.z + p3 * a.w;
        gF += p0 * b.x + p1 * b.y + p2 * b.z + p3 * b.w;
        gG += p0 * g.x + p1 * g.y + p2 * g.z + p3 * g.w;
        gO += p0 * o.x + p1 * o.y + p2 * o.z + p3 * o.w;
      }
      float ig = sigf(gI), fg = sigf(gF), og = sigf(gO), gg = tanhfast(gG);
      float cnew = fg * cpa[jj] + ig * gg;
      float hnew = og * tanhfast(cnew);
      cn[jj] = cnew; hn[jj] = hnew;
      oacc += fmaxf(hnew, 0.0f) * linw[j];
    }
    hout4[jc] = make_float4(hn[0], hn[1], hn[2], hn[3]);
    cout4[jc] = make_float4(cn[0], cn[1], cn[2], cn[3]);
  }
  out[i] = oacc;
}

extern "C" void kernel_launch(void* const* d_in, const int* in_sizes, int n_in,
                              void* d_out, int out_size, void* d_ws, size_t ws_size,
                              hipStream_t stream) {
  const float* x     = (const float*)d_in[0];
  const int*   ei    = (const int*)d_in[1];
  const float* ew    = (const float*)d_in[2];
  const float* h0    = (const float*)d_in[3];
  const float* c0    = (const float*)d_in[4];
  const float* convw = (const float*)d_in[5];
  const float* gwi   = (const float*)d_in[6];
  const float* gwh   = (const float*)d_in[7];
  const float* gbi   = (const float*)d_in[8];
  const float* gbh   = (const float*)d_in[9];
  const float* lwi   = (const float*)d_in[10];
  const float* lwh   = (const float*)d_in[11];
  const float* lbi   = (const float*)d_in[12];
  const float* lbh   = (const float*)d_in[13];
  const float* linw  = (const float*)d_in[14];
  const float* linb  = (const float*)d_in[15];

  int n = in_sizes[0] / 4;   // N nodes
  int E = in_sizes[1] / 2;   // edges

  float* out  = (float*)d_out;
  float* hout = out + n;
  float* cout = hout + (size_t)n * 32;

  int B = (n + BMASK) >> B_SHIFT;                    // buckets (<=1024 req'd)
  size_t need = (size_t)E * 8 + (size_t)n * 16 + ((size_t)3 * B + 2) * 4 + 64;

  if (B <= 1024 && ws_size >= need) {
    // ---- fast binned path ----
    int2*  binned = (int2*)d_ws;                     // E records
    float* m      = (float*)(binned + E);            // N*4
    int*   gCnt   = (int*)(m + (size_t)n * 4);       // B
    int*   start  = gCnt + B;                        // B+1
    int*   cursor = start + B + 1;                   // B

    hipMemsetAsync(gCnt, 0, (size_t)B * sizeof(int), stream);
    conv_m_kernel<<<(n + NTHR - 1) / NTHR, NTHR, 0, stream>>>(x, convw, m, n);

    int nbBlocks = (E + CHUNK - 1) / CHUNK;
    hist_kernel<<<nbBlocks, NTHR, 0, stream>>>(ei + E, E, B, gCnt);
    scan_kernel<<<1, 1024, 0, stream>>>(gCnt, B, start, cursor);
    bin_kernel<<<nbBlocks, NTHR, 0, stream>>>(ei, ew, E, B, cursor, binned);

    agg_node_kernel<<<B, NTHR, 0, stream>>>(
        x, m, binned, start, h0, c0,
        gwi, gwh, gbi, gbh, lwi, lwh, lbi, lbh, linw, linb,
        out, hout, cout, n);
  } else {
    // ---- fallback: global-atomic scatter (known correct) ----
    float* m      = (float*)d_ws;
    float* summed = m + (size_t)n * 4;
    float* cntp   = summed + (size_t)n * 4;
    hipMemsetAsync(summed, 0, (size_t)n * 5 * sizeof(float), stream);
    conv_m_kernel<<<(n + NTHR - 1) / NTHR, NTHR, 0, stream>>>(x, convw, m, n);
    int et = (E + 3) / 4;
    edge_kernel<<<(et + NTHR - 1) / NTHR, NTHR, 0, stream>>>(ei, ew, m, summed, cntp, E);
    node_kernel<<<(n + NTHR - 1) / NTHR, NTHR, 0, stream>>>(
        x, summed, cntp, h0, c0,
        gwi, gwh, gbi, gbh, lwi, lwh, lbi, lbh, linw, linb,
        out, hout, cout, n);
  }
}